// Round 7
// baseline (176.388 us; speedup 1.0000x reference)
//
#include <hip/hip_runtime.h>

// MultiModelMLP, round 7: memset + 2 kernels.
// K1 bucket_img (256 blocks): fp16 weight image (4 blocks/model) + 1-pass
//    register-queue bucketing with FOUR two-ended cursors per model
//    (class = blockIdx&3) -> only 64 same-address atomics per cursor.
// K2 mlp: fp16-MFMA, wave = 32 samples (ti=2), LDS 18 KB/block ->
//    launch_bounds(256,6) = 24 waves/CU; hole-validity masks, no clamping.

#define NM    64
#define HIDD  64
#define INF   6
#define OUTF  3
#define CAP   4864            // per-model region; two halves of RHALF each
#define RHALF 2432            // class 0 fwd from 0, class 1 bwd to RHALF,
                              // class 2 fwd from RHALF, class 3 bwd to CAP
#define NBLKB 256

#define CSTRIDE   32
#define O_CURSORS 0           // (m*4+class)*CSTRIDE, 64*4*32 ints
#define O_ORDER   8192        // NM*CAP sample ids
#define IWS_INTS  (O_ORDER + NM * CAP)
// then: xs fp16[NM*CAP*8], then weight image.

// fp16 image per model, fragment-major (slot s in [0,1920), lane l = s&63
// holds its v8h at half-offset s*8):
//   f = s>>6:  f<4: L0 mt=f (K padded 6->32)
//              f<28: L1..3: l=(f-4)>>3, mt=((f-4)&7)>>1, kh=(f-4)&1
//              else: L4 kh=f-28 (rows padded 3->16)
// floats at byte CONST_B: l=0..3 {bias[64], g[64], h[64]}, B4[3], pad.
#define CONST_B   30720
#define NCONSTF   784
#define IMG_BYTES 33856

#define HST 72                // halves per sample row in s_H (144 B)

typedef _Float16 v8h __attribute__((ext_vector_type(8)));
typedef _Float16 v4h __attribute__((ext_vector_type(4)));
typedef float    v4f __attribute__((ext_vector_type(4)));

// ------------------------------------------------------------ kernel 1 ----
__global__ __launch_bounds__(256, 4) void bucket_img_kernel(
    const int* __restrict__ idx, const float* __restrict__ x, int n,
    const float* __restrict__ W0, const float* __restrict__ W1,
    const float* __restrict__ W2, const float* __restrict__ W3,
    const float* __restrict__ W4,
    const float* __restrict__ B0, const float* __restrict__ G0, const float* __restrict__ H0,
    const float* __restrict__ B1, const float* __restrict__ G1, const float* __restrict__ H1,
    const float* __restrict__ B2, const float* __restrict__ G2, const float* __restrict__ H2,
    const float* __restrict__ B3, const float* __restrict__ G3, const float* __restrict__ H3,
    const float* __restrict__ B4,
    int* __restrict__ iws, _Float16* __restrict__ xs,
    unsigned char* __restrict__ imgbase) {
    __shared__ int lcnt[NM], lbase[NM];
    const int b = blockIdx.x, t = threadIdx.x;
    const int m = b >> 2, sub = b & 3;        // 4 blocks build each model image
    const int cls = b & 3;                    // cursor class for bucketing

    // ---- fragment-major image: 1920 v8h slots per model ----
    _Float16* img = (_Float16*)(imgbase + (size_t)m * IMG_BYTES);
    float* cst = (float*)(imgbase + (size_t)m * IMG_BYTES + CONST_B);
    for (int s = sub * 256 + t; s < 1920; s += 1024) {
        int f = s >> 6, l = s & 63;
        int c = l & 15, q = l >> 4;
        float vals[8];
        if (f < 4) {                          // layer 0, mt = f
            const float* wr = W0 + m * 384 + (f * 16 + c) * 6;
#pragma unroll
            for (int j = 0; j < 8; j++) {
                int k = q * 8 + j;
                vals[j] = (k < INF) ? wr[k] : 0.0f;
            }
        } else if (f < 28) {                  // layers 1..3
            int ll = (f - 4) >> 3, fb = (f - 4) & 7;
            int mt = fb >> 1, kh = fb & 1;
            const float* W = (ll == 0) ? W1 : (ll == 1) ? W2 : W3;
            const float* wr = W + m * 4096 + (mt * 16 + c) * 64 + kh * 32 + q * 8;
#pragma unroll
            for (int j = 0; j < 8; j++) vals[j] = wr[j];
        } else {                              // layer 4, kh = f-28
            int kh = f - 28;
            const float* wr = W4 + m * 192 + c * 64 + kh * 32 + q * 8;
#pragma unroll
            for (int j = 0; j < 8; j++) vals[j] = (c < OUTF) ? wr[j] : 0.0f;
        }
        v8h o;
#pragma unroll
        for (int j = 0; j < 8; j++) o[j] = (_Float16)vals[j];
        *(v8h*)(img + (size_t)s * 8) = o;
    }
    {   // consts (one pass: sub*256+t covers [0,1024) > NCONSTF)
        const float* lsrc[12] = {B0, G0, H0, B1, G1, H1, B2, G2, H2, B3, G3, H3};
        int e = sub * 256 + t;
        if (e < NCONSTF) {
            float v = 0.0f;
            if (e < 768) {
                int l = e / 192, r = e - l * 192;
                v = lsrc[l * 3 + (r >> 6)][m * 64 + (r & 63)];
            } else if (e < 771) {
                v = B4[m * 3 + (e - 768)];
            }
            cst[e] = v;
        }
    }

    // ---- bucketing: register queue + LDS ranks + 1 atomic/(block,model) ----
    if (t < NM) lcnt[t] = 0;
    __syncthreads();
    const int per = (n + NBLKB - 1) / NBLKB;   // 1024
    const int beg = b * per, end = min(n, beg + per);
    int sidq[4], mmq[4], rrq[4];
    int qn = 0;
    for (int i = beg + t; i < end; i += 256) { // qn <= 4
        sidq[qn] = i;
        mmq[qn] = idx[i];
        rrq[qn] = atomicAdd(&lcnt[mmq[qn]], 1);    // LDS only
        qn++;
    }
    __syncthreads();
    if (t < NM)
        lbase[t] = atomicAdd(&iws[O_CURSORS + (t * 4 + cls) * CSTRIDE], lcnt[t]);
    __syncthreads();
    for (int j = 0; j < qn; j++) {
        int mm = mmq[j];
        int rel;
        switch (cls) {                          // two-ended, two half-regions
            case 0:  rel = lbase[mm] + rrq[j]; break;
            case 1:  rel = RHALF - lbase[mm] - lcnt[mm] + rrq[j]; break;
            case 2:  rel = RHALF + lbase[mm] + rrq[j]; break;
            default: rel = CAP - lbase[mm] - lcnt[mm] + rrq[j]; break;
        }
        int slot = mm * CAP + rel;
        iws[O_ORDER + slot] = sidq[j];
        const float* xp = x + (size_t)sidq[j] * 6;   // coalesced read
        float2 a0 = *(const float2*)(xp);
        float2 a1 = *(const float2*)(xp + 2);
        float2 a2 = *(const float2*)(xp + 4);
        v8h o = {};
        o[0] = (_Float16)a0.x; o[1] = (_Float16)a0.y;
        o[2] = (_Float16)a1.x; o[3] = (_Float16)a1.y;
        o[4] = (_Float16)a2.x; o[5] = (_Float16)a2.y;
        *(v8h*)(xs + (size_t)slot * 8) = o;          // 16 B, run-contiguous
    }
}

// ------------------------------------------------------------ kernel 2 ----
// LN epilogue: D includes bias (MFMA C-operand). Reduce 64 features =
// 16 regs + lane+16/+32 butterflies; y = fma(v, a, fma(-mu, a, h)), a = rs*g.
// gg/hh loaded here (L1-hot, 16-lane-replicated) to keep VGPR <= ~84.
__device__ __forceinline__ void layer_epilogue(v4f D[4],
                                               const float* __restrict__ cb,
                                               int q, _Float16* __restrict__ st) {
    float S = 0.0f, Q2 = 0.0f;
#pragma unroll
    for (int mt = 0; mt < 4; mt++)
#pragma unroll
        for (int r = 0; r < 4; r++) {
            float v = D[mt][r];
            S += v;
            Q2 = fmaf(v, v, Q2);
        }
    S += __shfl_xor(S, 16, 64);
    S += __shfl_xor(S, 32, 64);
    Q2 += __shfl_xor(Q2, 16, 64);
    Q2 += __shfl_xor(Q2, 32, 64);
    float mu = S * (1.0f / 64.0f);
    float var = Q2 * (1.0f / 64.0f) - mu * mu;
    float rs = rsqrtf(var + 1e-5f);
#pragma unroll
    for (int mt = 0; mt < 4; mt++) {
        v4f g = *(const v4f*)(cb + 64 + mt * 16 + q * 4);
        v4f h = *(const v4f*)(cb + 128 + mt * 16 + q * 4);
        v4h o;
#pragma unroll
        for (int r = 0; r < 4; r++) {
            float a = g[r] * rs;
            float bb = fmaf(-mu, a, h[r]);
            o[r] = (_Float16)fmaxf(fmaf(D[mt][r], a, bb), 0.0f);
        }
        *(v4h*)(st + mt * 16) = o;
    }
}

__global__ __launch_bounds__(256, 6) void mlp_kernel(
    const int* __restrict__ iws, const _Float16* __restrict__ xs,
    const unsigned char* __restrict__ imgbase, float* __restrict__ out) {
    // Per-wave H^T buffer: 32 samples x 72 halves (4.5 KB/wave, 18 KB/block).
    __shared__ __align__(16) _Float16 s_H[4 * 32 * HST];

    const int m = blockIdx.y;
    const int a0 = iws[O_CURSORS + (m * 4 + 0) * CSTRIDE];
    const int a1 = iws[O_CURSORS + (m * 4 + 1) * CSTRIDE];
    const int a2 = iws[O_CURSORS + (m * 4 + 2) * CSTRIDE];
    const int a3 = iws[O_CURSORS + (m * 4 + 3) * CSTRIDE];
    // valid rel slots: [0,a0) U [RHALF-a1, RHALF+a2) U [CAP-a3, CAP)
    const int B0 = blockIdx.x * 128, B1 = B0 + 128;
    if (!((B0 < a0) | ((B1 > RHALF - a1) & (B0 < RHALF + a2)) | (B1 > CAP - a3)))
        return;                                // no barriers: safe

    const int t = threadIdx.x, w = t >> 6, lane = t & 63;
    const int c = lane & 15, q = lane >> 4;
    const int W0r = B0 + w * 32, W1r = W0r + 32;
    if (!((W0r < a0) | ((W1r > RHALF - a1) & (W0r < RHALF + a2)) | (W1r > CAP - a3)))
        return;

    const _Float16* img = (const _Float16*)(imgbase + (size_t)m * IMG_BYTES);
    const float* cf = (const float*)(imgbase + (size_t)m * IMG_BYTES + CONST_B);
    _Float16* Hw = s_H + w * (32 * HST);
    const int* order = iws + O_ORDER;

    int sid[2], vld[2], slot[2];
#pragma unroll
    for (int ti = 0; ti < 2; ti++) {
        int rel = W0r + ti * 16 + c;
        vld[ti] = (rel < a0) | ((rel >= RHALF - a1) & (rel < RHALF + a2)) |
                  (rel >= CAP - a3);
        slot[ti] = m * CAP + rel;              // always in [0, NM*CAP)
        sid[ti] = order[slot[ti]];             // garbage if !vld: never stored
    }

    // ---- layer 0: K=6 padded to 32; B-frag = packed xs slot ----
    {
        v8h A[4];
#pragma unroll
        for (int mt = 0; mt < 4; mt++)
            A[mt] = *(const v8h*)(img + mt * 512 + lane * 8);
        v4f bias[4];
#pragma unroll
        for (int mt = 0; mt < 4; mt++)
            bias[mt] = *(const v4f*)(cf + mt * 16 + q * 4);
#pragma unroll
        for (int ti = 0; ti < 2; ti++) {
            v8h bfr = {};
            if (q == 0) bfr = *(const v8h*)(xs + (size_t)slot[ti] * 8);
            v4f D[4];
#pragma unroll
            for (int mt = 0; mt < 4; mt++)
                D[mt] = __builtin_amdgcn_mfma_f32_16x16x32_f16(A[mt], bfr, bias[mt], 0, 0, 0);
            layer_epilogue(D, cf, q, Hw + (ti * 16 + c) * HST + q * 4);
        }
    }

    // ---- layers 1..3: fully unrolled (A-loads hoist into prior epilogue) ----
#pragma unroll
    for (int l = 1; l <= 3; l++) {
        const _Float16* wp = img + 2048 + (l - 1) * 4096 + lane * 8;
        v8h A[4][2];
#pragma unroll
        for (int mt = 0; mt < 4; mt++)
#pragma unroll
            for (int kh = 0; kh < 2; kh++)
                A[mt][kh] = *(const v8h*)(wp + (mt * 2 + kh) * 512);
        const float* cb = cf + l * 192;
        v4f bias[4];
#pragma unroll
        for (int mt = 0; mt < 4; mt++)
            bias[mt] = *(const v4f*)(cb + mt * 16 + q * 4);
#pragma unroll
        for (int ti = 0; ti < 2; ti++) {
            const _Float16* hp = Hw + (ti * 16 + c) * HST;
            v8h b0 = *(const v8h*)(hp + q * 8);
            v8h b1 = *(const v8h*)(hp + 32 + q * 8);
            v4f D[4];
#pragma unroll
            for (int mt = 0; mt < 4; mt++) {
                D[mt] = __builtin_amdgcn_mfma_f32_16x16x32_f16(A[mt][0], b0, bias[mt], 0, 0, 0);
                D[mt] = __builtin_amdgcn_mfma_f32_16x16x32_f16(A[mt][1], b1, D[mt], 0, 0, 0);
            }
            layer_epilogue(D, cb, q, Hw + (ti * 16 + c) * HST + q * 4);
        }
    }

    // ---- layer 4: 64 -> 3 (rows padded to 16) ----
    {
        const _Float16* wp = img + 14336 + lane * 8;
        v8h A0 = *(const v8h*)(wp);
        v8h A1 = *(const v8h*)(wp + 512);
        v4f b4i = {cf[768], cf[769], cf[770], 0.0f};
#pragma unroll
        for (int ti = 0; ti < 2; ti++) {
            const _Float16* hp = Hw + (ti * 16 + c) * HST;
            v8h b0 = *(const v8h*)(hp + q * 8);
            v8h b1 = *(const v8h*)(hp + 32 + q * 8);
            v4f D = __builtin_amdgcn_mfma_f32_16x16x32_f16(A0, b0, b4i, 0, 0, 0);
            D = __builtin_amdgcn_mfma_f32_16x16x32_f16(A1, b1, D, 0, 0, 0);
            if (q == 0 && vld[ti]) {
                float* op = out + (size_t)sid[ti] * 3;
                op[0] = D[0]; op[1] = D[1]; op[2] = D[2];
            }
        }
    }
}

// -------------------------------------------------------------- launch ----
extern "C" void kernel_launch(void* const* d_in, const int* in_sizes, int n_in,
                              void* d_out, int out_size, void* d_ws, size_t ws_size,
                              hipStream_t stream) {
    const float* x  = (const float*)d_in[0];
    const int*  idx = (const int*)d_in[1];
    const float* W0 = (const float*)d_in[2];
    const float* B0 = (const float*)d_in[3];
    const float* G0 = (const float*)d_in[4];
    const float* H0 = (const float*)d_in[5];
    const float* W1 = (const float*)d_in[6];
    const float* B1 = (const float*)d_in[7];
    const float* G1 = (const float*)d_in[8];
    const float* H1 = (const float*)d_in[9];
    const float* W2 = (const float*)d_in[10];
    const float* B2 = (const float*)d_in[11];
    const float* G2 = (const float*)d_in[12];
    const float* H2 = (const float*)d_in[13];
    const float* W3 = (const float*)d_in[14];
    const float* B3 = (const float*)d_in[15];
    const float* G3 = (const float*)d_in[16];
    const float* H3 = (const float*)d_in[17];
    const float* W4 = (const float*)d_in[18];
    const float* B4 = (const float*)d_in[19];
    float* out = (float*)d_out;

    int n = in_sizes[1];
    int* iws = (int*)d_ws;
    _Float16* xs = (_Float16*)((char*)d_ws + (size_t)IWS_INTS * 4);
    unsigned char* imgbase =
        (unsigned char*)d_ws + (size_t)IWS_INTS * 4 + (size_t)NM * CAP * 16;

    hipMemsetAsync(d_ws, 0, NM * 4 * CSTRIDE * sizeof(int), stream);  // cursors
    bucket_img_kernel<<<dim3(NBLKB), 256, 0, stream>>>(
        idx, x, n, W0, W1, W2, W3, W4,
        B0, G0, H0, B1, G1, H1, B2, G2, H2, B3, G3, H3, B4, iws, xs, imgbase);
    // grid.x = CAP/128 = 38 chunks of 128 samples per model.
    mlp_kernel<<<dim3(38, NM), 256, 0, stream>>>(iws, xs, imgbase, out);
}